// Round 8
// baseline (194.062 us; speedup 1.0000x reference)
//
#include <hip/hip_runtime.h>
#include <stdint.h>

typedef __attribute__((ext_vector_type(8))) short short8;
typedef __attribute__((ext_vector_type(8))) unsigned short u16x8;
typedef __attribute__((ext_vector_type(4))) float f32x4;

__device__ __forceinline__ uint16_t f2bf(float x) {
  uint32_t u = __float_as_uint(x);
  uint32_t r = (u + 0x7FFFu + ((u >> 16) & 1u)) >> 16;
  return (uint16_t)r;
}
__device__ __forceinline__ float bf2f(uint16_t x) {
  return __uint_as_float(((uint32_t)x) << 16);
}

// async global->LDS, 16B per lane. LDS dest = wave-uniform base (HW adds lane*16).
__device__ __forceinline__ void gl_lds16(const uint16_t* g, void* l) {
  __builtin_amdgcn_global_load_lds(
      (const __attribute__((address_space(1))) void*)g,
      (__attribute__((address_space(3))) void*)l, 16, 0, 0);
}

// ---------------- conversion kernels ----------------

__global__ __launch_bounds__(256) void cvt_f32_to_bf16(const float* __restrict__ in,
                                                       uint16_t* __restrict__ out) {
  long i = ((long)blockIdx.x * 256 + threadIdx.x) * 8;
  f32x4 v0 = *(const f32x4*)(in + i);
  f32x4 v1 = *(const f32x4*)(in + i + 4);
  u16x8 o;
  o[0] = f2bf(v0[0]); o[1] = f2bf(v0[1]); o[2] = f2bf(v0[2]); o[3] = f2bf(v0[3]);
  o[4] = f2bf(v1[0]); o[5] = f2bf(v1[1]); o[6] = f2bf(v1[2]); o[7] = f2bf(v1[3]);
  *(u16x8*)(out + i) = o;
}

// W [1024][1024] f32 -> WT [1024(n)][1024(k)] bf16 (3 matrices via blockIdx.z)
__global__ __launch_bounds__(64) void cvt_w_transpose(const float* __restrict__ W0,
                                                      const float* __restrict__ W1,
                                                      const float* __restrict__ W2,
                                                      uint16_t* __restrict__ WT) {
  const int z = blockIdx.z;
  const float* W = (z == 0) ? W0 : ((z == 1) ? W1 : W2);
  uint16_t* out = WT + (long)z * 1024 * 1024;
  const int n = blockIdx.x * 64 + threadIdx.x;
  const int k0 = blockIdx.y * 128;
  for (int kk = 0; kk < 128; kk += 8) {
    u16x8 o;
#pragma unroll
    for (int j = 0; j < 8; j++) o[j] = f2bf(W[(long)(k0 + kk + j) * 1024 + n]);
    *(u16x8*)(out + (long)n * 1024 + k0 + kk) = o;
  }
}

// V [4*2048][1024] bf16 -> Vt [4][1024(d)][2048(s)] bf16
__global__ __launch_bounds__(256) void transpose_v(const uint16_t* __restrict__ V,
                                                   uint16_t* __restrict__ Vt) {
  __shared__ uint16_t tile[64][66];
  const int b = blockIdx.z;
  const int s0 = blockIdx.x * 64, d0 = blockIdx.y * 64;
  const int t = threadIdx.x;
  const int r = t >> 3, c = (t & 7) * 8;
  const uint16_t* Vb = V + (long)b * 2048 * 1024;
#pragma unroll
  for (int j = 0; j < 2; j++) {
    u16x8 v = *(const u16x8*)(Vb + (long)(s0 + r + 32 * j) * 1024 + d0 + c);
#pragma unroll
    for (int i = 0; i < 8; i++) tile[r + 32 * j][c + i] = v[i];
  }
  __syncthreads();
  uint16_t* Vtb = Vt + (long)b * 1024 * 2048;
#pragma unroll
  for (int j = 0; j < 2; j++) {
    const int d = r + 32 * j;
    u16x8 o;
#pragma unroll
    for (int i = 0; i < 8; i++) o[i] = tile[c + i][d];
    *(u16x8*)(Vtb + (long)(d0 + d) * 2048 + s0 + c) = o;
  }
}

// ============ generalized 8-wave NT GEMM: C[M,N] = A[M,K]*B[N,K]^T ==========
// AI=8: BM=256, 4 phases/K-tile; AI=4: BM=128, 2 phases/K-tile. BN=256, BK=64,
// 8 waves (2M x 4N). LDS dbuf: A (BM*128B) then B (32KB). XOR-swizzle
// (row&7)<<4 on 16B slots; gl_lds writes linearly -> inverse-swizzled global
// source; ds_reads apply the same XOR. bR[4][2] preloaded in phase 0 (no
// phase-3 re-read). Counted vmcnt once per K-tile; never 0 in main loop.
// Epilogue: acc frags -> LDS transpose (f32 [2][16][260]) -> coalesced stores.
// MODE 0: fused QKV proj, C=bf16(acc+bias), slab/bias by bn>>2.
// MODE 1: C=bf16(exp(acc*scale+mask)); row-sums atomicAdd into lsum.
// MODE 2: C=f32(acc / lsum[row]).
template <int MODE, int AI>
__global__ __launch_bounds__(512, 2) void gemmX(
    const uint16_t* __restrict__ Abase, long sAz,
    const uint16_t* __restrict__ Bbase, long sBz,
    int K, int N,
    char* __restrict__ Cbase, long sCz,
    const float* __restrict__ e0, const float* __restrict__ e1,
    const float* __restrict__ e2,
    const float* __restrict__ maskb, long sMz, float scale,
    float* __restrict__ lsum) {
  constexpr int BM = AI * 32;
  constexpr int ABYTES = BM * 128;          // A region bytes per buffer
  constexpr int BUFB = ABYTES + 32768;      // per-dbuf stride
  __shared__ __align__(16) char lds[2 * BUFB];
  const int t = threadIdx.x;
  const int lane = t & 63;
  const int w = t >> 6;
  const int bm = blockIdx.x, bn = blockIdx.y, bz = blockIdx.z;
  const uint16_t* A = (const uint16_t*)((const char*)Abase + (long)bz * sAz);
  const uint16_t* B = (const uint16_t*)((const char*)Bbase + (long)bz * sBz);

  // staging geometry: shot = 512 threads x 16B = 8KB = 64 rows x 128B.
  const int srow = t >> 3;
  const int scol = ((((t & 7) * 16) ^ ((srow & 7) << 4)) >> 1);  // bf16 elems
  const uint16_t* gA[4];
  const uint16_t* gB[4];
#pragma unroll
  for (int s = 0; s < 4; s++) {
    gA[s] = A + (long)(bm * BM + (s % (AI / 2)) * 64 + srow) * K + scol;
    gB[s] = B + (long)(bn * 256 + s * 64 + srow) * K + scol;
  }

  const int wm = w >> 2, wn = w & 3;
  const int fr = lane & 15, kg = lane >> 4;
  const int X = (fr & 7) << 4;
  const int aRow = (wm * (AI * 16) + fr) * 128 + kg * 16;
  const int bRow = (wn * 64 + fr) * 128 + kg * 16;

  f32x4 acc[AI][4];
#pragma unroll
  for (int i = 0; i < AI; i++)
#pragma unroll
    for (int j = 0; j < 4; j++) acc[i][j] = (f32x4){0.f, 0.f, 0.f, 0.f};

  short8 aR[4][2], bR[4][2];
  const int NT = K >> 6;

#define ARD(off, i, ks) (*(const short8*)(lds + (off) + ((aRow + (i) * 2048 + (ks) * 64) ^ X)))
#define BRD(off, j, ks) (*(const short8*)(lds + ABYTES + (off) + ((bRow + (j) * 2048 + (ks) * 64) ^ X)))
#define STG_A01(off, ko) { gl_lds16(gA[0] + (ko), lds + (off) + w * 1024); \
                           gl_lds16(gA[1] + (ko), lds + (off) + 8192 + w * 1024); }
#define STG_A23(off, ko) { gl_lds16(gA[2] + (ko), lds + (off) + 16384 + w * 1024); \
                           gl_lds16(gA[3] + (ko), lds + (off) + 24576 + w * 1024); }
#define STG_B01(off, ko) { gl_lds16(gB[0] + (ko), lds + ABYTES + (off) + w * 1024); \
                           gl_lds16(gB[1] + (ko), lds + ABYTES + (off) + 8192 + w * 1024); }
#define STG_B23(off, ko) { gl_lds16(gB[2] + (ko), lds + ABYTES + (off) + 16384 + w * 1024); \
                           gl_lds16(gB[3] + (ko), lds + ABYTES + (off) + 24576 + w * 1024); }
#define LGKM0 { asm volatile("s_waitcnt lgkmcnt(0)" ::: "memory"); __builtin_amdgcn_sched_barrier(0); }
#define MFMA16(I0, J0)                                                            \
  __builtin_amdgcn_s_setprio(1);                                                  \
  _Pragma("unroll") for (int i = 0; i < 4; i++)                                   \
  _Pragma("unroll") for (int j = 0; j < 2; j++)                                   \
  _Pragma("unroll") for (int ks = 0; ks < 2; ks++)                                \
    acc[(I0) + i][(J0) + j] = __builtin_amdgcn_mfma_f32_16x16x32_bf16(            \
        aR[i][ks], bR[(J0) + j][ks], acc[(I0) + i][(J0) + j], 0, 0, 0);           \
  __builtin_amdgcn_s_setprio(0);

  // prologue: tile 0 -> buf 0
  if constexpr (AI == 8) { STG_A01(0, 0); STG_A23(0, 0); }
  else                   { STG_A01(0, 0); }
  STG_B01(0, 0); STG_B23(0, 0);

  int curo = 0;
  for (int tt = 0; tt < NT - 1; ++tt) {
    const int nxto = curo ^ BUFB;
    const int ko = (tt + 1) << 6;
    if constexpr (AI == 8) {
      // ---- phase 0: (i0-3, j0-1); preload ALL bR
      STG_A01(nxto, ko);
      asm volatile("s_waitcnt vmcnt(2)" ::: "memory");
      __builtin_amdgcn_s_barrier();
      __builtin_amdgcn_sched_barrier(0);
#pragma unroll
      for (int i = 0; i < 4; i++) { aR[i][0] = ARD(curo, i, 0); aR[i][1] = ARD(curo, i, 1); }
#pragma unroll
      for (int j = 0; j < 4; j++) { bR[j][0] = BRD(curo, j, 0); bR[j][1] = BRD(curo, j, 1); }
      LGKM0;
      MFMA16(0, 0);
      __builtin_amdgcn_s_barrier();
      // ---- phase 1: (i0-3, j2-3) — bR already live
      STG_A23(nxto, ko);
      __builtin_amdgcn_s_barrier();
      MFMA16(0, 2);
      __builtin_amdgcn_s_barrier();
      // ---- phase 2: (i4-7, j2-3)
      STG_B01(nxto, ko);
#pragma unroll
      for (int i = 0; i < 4; i++) { aR[i][0] = ARD(curo, 4 + i, 0); aR[i][1] = ARD(curo, 4 + i, 1); }
      __builtin_amdgcn_s_barrier();
      LGKM0;
      MFMA16(4, 2);
      __builtin_amdgcn_s_barrier();
      // ---- phase 3: (i4-7, j0-1)
      STG_B23(nxto, ko);
      __builtin_amdgcn_s_barrier();
      MFMA16(4, 0);
      __builtin_amdgcn_s_barrier();
    } else {
      // ---- phase 0: (i0-3, j0-1); preload ALL bR; issue 4 of 6 loads
      STG_A01(nxto, ko);
      STG_B01(nxto, ko);
      asm volatile("s_waitcnt vmcnt(4)" ::: "memory");
      __builtin_amdgcn_s_barrier();
      __builtin_amdgcn_sched_barrier(0);
#pragma unroll
      for (int i = 0; i < 4; i++) { aR[i][0] = ARD(curo, i, 0); aR[i][1] = ARD(curo, i, 1); }
#pragma unroll
      for (int j = 0; j < 4; j++) { bR[j][0] = BRD(curo, j, 0); bR[j][1] = BRD(curo, j, 1); }
      LGKM0;
      MFMA16(0, 0);
      __builtin_amdgcn_s_barrier();
      // ---- phase 1: (i0-3, j2-3); issue remaining 2 loads
      STG_B23(nxto, ko);
      __builtin_amdgcn_s_barrier();
      MFMA16(0, 2);
      __builtin_amdgcn_s_barrier();
    }
    curo = nxto;
  }
  // ---- tail tile: drain all loads once
  asm volatile("s_waitcnt vmcnt(0)" ::: "memory");
  __builtin_amdgcn_s_barrier();
  __builtin_amdgcn_sched_barrier(0);
#pragma unroll
  for (int i = 0; i < 4; i++) { aR[i][0] = ARD(curo, i, 0); aR[i][1] = ARD(curo, i, 1); }
#pragma unroll
  for (int j = 0; j < 4; j++) { bR[j][0] = BRD(curo, j, 0); bR[j][1] = BRD(curo, j, 1); }
  LGKM0;
  MFMA16(0, 0);
  MFMA16(0, 2);
  if constexpr (AI == 8) {
#pragma unroll
    for (int i = 0; i < 4; i++) { aR[i][0] = ARD(curo, 4 + i, 0); aR[i][1] = ARD(curo, 4 + i, 1); }
    LGKM0;
    MFMA16(4, 2);
    MFMA16(4, 0);
  }

  // ================= transpose epilogue through LDS =================
  // eL: f32 [2 slabs][16 rows][RS=260]; writer banks 2-way max, reader
  // f32x4 conflict-free (row16*260 mod 32 = 4*row16 tiles the banks).
  __syncthreads();  // all K-loop LDS reads consumed; safe to reuse lds
  constexpr int RS = 260;
  float* eL = (float*)lds;
  const int wboff = wm * (16 * RS) + (kg * 4) * RS + wn * 64 + fr;
  const int lr = t >> 4, slab = lr >> 4, row16 = lr & 15, cj = t & 15;
  const float* rb = eL + slab * (16 * RS) + row16 * RS + cj * 16;
  const int grow_base = bm * BM + slab * (AI * 16) + row16;

  // mode-invariant prefetches
  f32x4 bias4[4];
  const uint16_t* Cu16 = nullptr;
  float* Cf32 = nullptr;
  uint16_t* Cw = nullptr;
  int colg = 0;
  const float* mk = nullptr;
  if constexpr (MODE == 0) {
    const int zz = bn >> 2;
    const float* bias = (zz == 0) ? e0 : ((zz == 1) ? e1 : e2);
    colg = (bn & 3) * 256 + cj * 16;
#pragma unroll
    for (int q = 0; q < 4; q++) bias4[q] = *(const f32x4*)(bias + colg + q * 4);
    Cw = (uint16_t*)(Cbase + (long)zz * sCz);
  } else if constexpr (MODE == 1) {
    colg = bn * 256 + cj * 16;
    Cw = (uint16_t*)(Cbase + (long)bz * sCz);
    mk = (const float*)((const char*)maskb + (long)bz * sMz);
  } else {
    colg = bn * 256 + cj * 16;
    Cf32 = (float*)(Cbase + (long)bz * sCz);
  }
  (void)Cu16;

#pragma unroll
  for (int i = 0; i < AI; i++) {
    // writer: this thread's 16 values of chunk i
#pragma unroll
    for (int j = 0; j < 4; j++)
#pragma unroll
      for (int r = 0; r < 4; r++)
        eL[wboff + r * RS + j * 16] = acc[i][j][r];
    __syncthreads();
    // reader: one row, 16 contiguous cols
    f32x4 v0 = *(const f32x4*)(rb);
    f32x4 v1 = *(const f32x4*)(rb + 4);
    f32x4 v2 = *(const f32x4*)(rb + 8);
    f32x4 v3 = *(const f32x4*)(rb + 12);
    const int grow = grow_base + i * 16;
    if constexpr (MODE == 0) {
      v0 += bias4[0]; v1 += bias4[1]; v2 += bias4[2]; v3 += bias4[3];
      u16x8 o0, o1;
#pragma unroll
      for (int q = 0; q < 4; q++) {
        o0[q] = f2bf(v0[q]); o0[4 + q] = f2bf(v1[q]);
        o1[q] = f2bf(v2[q]); o1[4 + q] = f2bf(v3[q]);
      }
      uint16_t* dst = Cw + (long)grow * 1024 + colg;
      *(u16x8*)dst = o0;
      *(u16x8*)(dst + 8) = o1;
    } else if constexpr (MODE == 1) {
      const float* mrow = mk + (long)grow * N + colg;
      f32x4 m0 = *(const f32x4*)(mrow);
      f32x4 m1 = *(const f32x4*)(mrow + 4);
      f32x4 m2 = *(const f32x4*)(mrow + 8);
      f32x4 m3 = *(const f32x4*)(mrow + 12);
      float e[16];
#pragma unroll
      for (int q = 0; q < 4; q++) {
        e[q] = __expf(v0[q] * scale + m0[q]);
        e[4 + q] = __expf(v1[q] * scale + m1[q]);
        e[8 + q] = __expf(v2[q] * scale + m2[q]);
        e[12 + q] = __expf(v3[q] * scale + m3[q]);
      }
      float ps = 0.f;
#pragma unroll
      for (int q = 0; q < 16; q++) ps += e[q];
      ps += __shfl_xor(ps, 1);
      ps += __shfl_xor(ps, 2);
      ps += __shfl_xor(ps, 4);
      ps += __shfl_xor(ps, 8);
      if ((lane & 15) == 0) atomicAdd(lsum + (long)bz * 2048 + grow, ps);
      u16x8 o0, o1;
#pragma unroll
      for (int q = 0; q < 8; q++) { o0[q] = f2bf(e[q]); o1[q] = f2bf(e[8 + q]); }
      uint16_t* dst = Cw + (long)grow * N + colg;
      *(u16x8*)dst = o0;
      *(u16x8*)(dst + 8) = o1;
    } else {
      const float ri = 1.0f / lsum[(long)bz * 2048 + grow];
      v0 *= ri; v1 *= ri; v2 *= ri; v3 *= ri;
      float* dst = Cf32 + (long)grow * N + colg;
      *(f32x4*)dst = v0;
      *(f32x4*)(dst + 4) = v1;
      *(f32x4*)(dst + 8) = v2;
      *(f32x4*)(dst + 12) = v3;
    }
    __syncthreads();
  }
#undef ARD
#undef BRD
#undef STG_A01
#undef STG_A23
#undef STG_B01
#undef STG_B23
#undef LGKM0
#undef MFMA16
}

// ---------------- launch ----------------
extern "C" void kernel_launch(void* const* d_in, const int* in_sizes, int n_in,
                              void* d_out, int out_size, void* d_ws, size_t ws_size,
                              hipStream_t stream) {
  const float* hs = (const float*)d_in[0];
  const float* mask = (const float*)d_in[1];
  const float* Wq = (const float*)d_in[2];
  const float* bq = (const float*)d_in[3];
  const float* Wk = (const float*)d_in[4];
  const float* bk = (const float*)d_in[5];
  const float* Wv = (const float*)d_in[6];
  const float* bv = (const float*)d_in[7];
  float* out = (float*)d_out;

  char* ws = (char*)d_ws;
  uint16_t* hsb = (uint16_t*)ws;                  // [8192][1024] bf16    16MB
  uint16_t* WT = (uint16_t*)(ws + (16L << 20));   // [3][1024][1024]       6MB
  uint16_t* QKV = (uint16_t*)(ws + (22L << 20));  // [3][8192][1024]      48MB
  uint16_t* Vt = (uint16_t*)(ws + (70L << 20));   // [4][1024(d)][2048]   16MB
  uint16_t* E = (uint16_t*)(ws + (86L << 20));    // [4][2048][2048] bf16 32MB
  float* lsum = (float*)(ws + (118L << 20));      // [4][2048] f32        32KB

  // 1) hs -> bf16
  cvt_f32_to_bf16<<<4096, 256, 0, stream>>>(hs, hsb);
  // 2) W -> W^T bf16 (x3; contiguous => WT is [3072][1024])
  cvt_w_transpose<<<dim3(16, 8, 3), 64, 0, stream>>>(Wq, Wk, Wv, WT);
  // zero the row-sum accumulator (capture-legal async memset)
  hipMemsetAsync((void*)lsum, 0, 4L * 2048 * sizeof(float), stream);
  // 3) fused QKV projection: [8192x1024] x [3072x1024]^T, 128x256 tiles
  gemmX<0, 4><<<dim3(64, 12, 1), 512, 0, stream>>>(
      hsb, 0L, WT, 0L, 1024, 3072, (char*)QKV, 16L << 20,
      bq, bk, bv, nullptr, 0L, 0.f, nullptr);
  // 4) V transpose per batch
  transpose_v<<<dim3(32, 16, 4), 256, 0, stream>>>(QKV + 2L * 8192 * 1024, Vt);
  // 5) E = bf16(exp(Q K^T / 32 + mask)); row sums -> lsum (atomics)
  gemmX<1, 8><<<dim3(8, 8, 4), 512, 0, stream>>>(
      QKV, 4L << 20, QKV + 8192L * 1024, 4L << 20, 1024, 2048, (char*)E, 8L << 20,
      nullptr, nullptr, nullptr, mask, 16L << 20, 0.03125f, lsum);
  // 6) out = (E Vt^T) / lsum  (128x256, K=2048, f32 out)
  gemmX<2, 4><<<dim3(16, 4, 4), 512, 0, stream>>>(
      E, 8L << 20, Vt, 4L << 20, 2048, 1024, (char*)out, 8L << 20,
      nullptr, nullptr, nullptr, nullptr, 0L, 0.f, lsum);
}